// Round 5
// baseline (173.315 us; speedup 1.0000x reference)
//
#include <hip/hip_runtime.h>
#include <math.h>

#define BB 64
#define NN 2048
#define DZ 128
#define DA 64
#define DD 192
#define EE 16
#define HH 512
#define LN_EPS 1e-5f

__device__ __forceinline__ float mishf(float x) {
    float sp = (x > 20.f) ? x : log1pf(__expf(x));
    return x * tanhf(sp);
}

// ---------------- K1: weights[b,n,e] = sum_d x[b,n,d] * phi[d,e] ----------------
// Block: 256 thr = 4 waves: wave -> (eg, h); each thread: 2 tokens x 8 experts x 96-d half.
// Grid: 1024 blocks x 128 tokens. phi broadcast from LDS (wave-uniform addr -> free).

__device__ __forceinline__ void kw_load(float4* buf, const float* sA, const float* sB) {
#pragma unroll
    for (int q = 0; q < 4; q++) buf[q]     = ((const float4*)sA)[q];
#pragma unroll
    for (int q = 0; q < 4; q++) buf[4 + q] = ((const float4*)sB)[q];
}

__device__ __forceinline__ void kw_comp(const float4* buf, const float4* pf4,
                                        int kg0, int eg, float acc[2][8]) {
#pragma unroll
    for (int q = 0; q < 4; q++) {
        const float* va = (const float*)&buf[q];
        const float* vb = (const float*)&buf[4 + q];
#pragma unroll
        for (int c4 = 0; c4 < 4; c4++) {
            int kg = kg0 + q * 4 + c4;
            float p[8];
            *(float4*)&p[0] = pf4[kg * 4 + eg * 2];
            *(float4*)&p[4] = pf4[kg * 4 + eg * 2 + 1];
            float xa = va[c4], xb = vb[c4];
#pragma unroll
            for (int j = 0; j < 8; j++) {
                acc[0][j] += xa * p[j];
                acc[1][j] += xb * p[j];
            }
        }
    }
}

__global__ __launch_bounds__(256, 4)
void k_weights(const float* __restrict__ z, const float* __restrict__ a,
               const float* __restrict__ phi, float* __restrict__ w) {
    __shared__ float phis[DD * EE];      // 12 KB
    __shared__ float red[EE * 128];      // 8 KB   [e][tok_local]
    int t = threadIdx.x;
    for (int i = t; i < DD * EE / 4; i += 256)
        ((float4*)phis)[i] = ((const float4*)phi)[i];
    __syncthreads();

    const float4* pf4 = (const float4*)phis;
    int lane = t & 63, wave = t >> 6;
    int eg = wave & 1, h = wave >> 1;
    long tokbase = (long)blockIdx.x * 128;
    long tokA = tokbase + lane, tokB = tokA + 64;

    float acc[2][8];
#pragma unroll
    for (int tt = 0; tt < 2; tt++)
#pragma unroll
        for (int j = 0; j < 8; j++) acc[tt][j] = 0.f;

    auto src = [&](long tok, int g) -> const float* {
        int d0 = h * 96 + g * 16;
        return (d0 < DZ) ? (z + tok * DZ + d0) : (a + tok * DA + (d0 - DZ));
    };

    float4 A[8], Bv[8];
    kw_load(A, src(tokA, 0), src(tokB, 0));
#pragma unroll
    for (int g = 0; g < 6; g += 2) {
        kw_load(Bv, src(tokA, g + 1), src(tokB, g + 1));
        kw_comp(A, pf4, h * 96 + g * 16, eg, acc);
        if (g + 2 < 6) kw_load(A, src(tokA, g + 2), src(tokB, g + 2));
        kw_comp(Bv, pf4, h * 96 + (g + 1) * 16, eg, acc);
    }

    if (h == 1) {
#pragma unroll
        for (int tt = 0; tt < 2; tt++)
#pragma unroll
            for (int j = 0; j < 8; j++)
                red[(eg * 8 + j) * 128 + lane + tt * 64] = acc[tt][j];
    }
    __syncthreads();
    if (h == 0) {
#pragma unroll
        for (int tt = 0; tt < 2; tt++) {
            long token = tokbase + lane + tt * 64;
            float o[8];
#pragma unroll
            for (int j = 0; j < 8; j++)
                o[j] = acc[tt][j] + red[(eg * 8 + j) * 128 + lane + tt * 64];
            float4* wp = (float4*)(w + token * EE + eg * 8);
            wp[0] = make_float4(o[0], o[1], o[2], o[3]);
            wp[1] = make_float4(o[4], o[5], o[6], o[7]);
        }
    }
}

// ---------------- K2: softmax stats over n, chunked ----------------
#define RSTR 17
__global__ __launch_bounds__(256)
void k_stats1(const float* __restrict__ w, float* __restrict__ lmax,
              float* __restrict__ lsum) {
    __shared__ float red[256 * RSTR];
    int b = blockIdx.y, c = blockIdx.x, t = threadIdx.x;
    const float* wb = w + ((long)b * NN + c * 512) * EE;

    float m[EE];
#pragma unroll
    for (int e = 0; e < EE; e++) m[e] = -1e30f;
    for (int k = 0; k < 2; k++) {
        const float4* row = (const float4*)(wb + ((long)(k * 256 + t)) * EE);
#pragma unroll
        for (int q = 0; q < 4; q++) {
            float4 v = row[q];
            m[q * 4 + 0] = fmaxf(m[q * 4 + 0], v.x);
            m[q * 4 + 1] = fmaxf(m[q * 4 + 1], v.y);
            m[q * 4 + 2] = fmaxf(m[q * 4 + 2], v.z);
            m[q * 4 + 3] = fmaxf(m[q * 4 + 3], v.w);
        }
    }
#pragma unroll
    for (int e = 0; e < EE; e++) red[t * RSTR + e] = m[e];
    __syncthreads();
    for (int s = 128; s > 0; s >>= 1) {
        if (t < s) {
#pragma unroll
            for (int e = 0; e < EE; e++)
                red[t * RSTR + e] = fmaxf(red[t * RSTR + e], red[(t + s) * RSTR + e]);
        }
        __syncthreads();
    }
    float mg[EE];
#pragma unroll
    for (int e = 0; e < EE; e++) mg[e] = red[e];
    __syncthreads();

    float s_[EE];
#pragma unroll
    for (int e = 0; e < EE; e++) s_[e] = 0.f;
    for (int k = 0; k < 2; k++) {
        const float4* row = (const float4*)(wb + ((long)(k * 256 + t)) * EE);
#pragma unroll
        for (int q = 0; q < 4; q++) {
            float4 v = row[q];
            s_[q * 4 + 0] += __expf(v.x - mg[q * 4 + 0]);
            s_[q * 4 + 1] += __expf(v.y - mg[q * 4 + 1]);
            s_[q * 4 + 2] += __expf(v.z - mg[q * 4 + 2]);
            s_[q * 4 + 3] += __expf(v.w - mg[q * 4 + 3]);
        }
    }
#pragma unroll
    for (int e = 0; e < EE; e++) red[t * RSTR + e] = s_[e];
    __syncthreads();
    for (int s = 128; s > 0; s >>= 1) {
        if (t < s) {
#pragma unroll
            for (int e = 0; e < EE; e++)
                red[t * RSTR + e] += red[(t + s) * RSTR + e];
        }
        __syncthreads();
    }
    if (t < EE) {
        lmax[((long)b * 4 + c) * EE + t] = mg[t];
        lsum[((long)b * 4 + c) * EE + t] = red[t];
    }
}

__global__ __launch_bounds__(256)
void k_stats2(const float* __restrict__ lmax, const float* __restrict__ lsum,
              float* __restrict__ gmax, float* __restrict__ grcp) {
    int idx = blockIdx.x * 256 + threadIdx.x;    // (b,e), 1024 total
    if (idx >= BB * EE) return;
    int b = idx >> 4, e = idx & 15;
    float gm = -1e30f;
#pragma unroll
    for (int c = 0; c < 4; c++)
        gm = fmaxf(gm, lmax[((long)b * 4 + c) * EE + e]);
    float Z = 0.f;
#pragma unroll
    for (int c = 0; c < 4; c++)
        Z += __expf(lmax[((long)b * 4 + c) * EE + e] - gm) * lsum[((long)b * 4 + c) * EE + e];
    gmax[idx] = gm;
    grcp[idx] = 1.f / Z;
}

// ---------------- K3: xin[e,b,d] += sum_n dispatch[b,n,e] * x[b,n,d] ----------------
// 64-token chunks -> 2048 blocks (~8/CU) so HBM latency is hidden by TLP.
__global__ __launch_bounds__(192)
void k_xin(const float* __restrict__ z, const float* __restrict__ a,
           const float* __restrict__ w, const float* __restrict__ gmax,
           const float* __restrict__ grcp, float* __restrict__ xin) {
    __shared__ float disp[64 * EE];   // 4 KB
    int b = blockIdx.y, chunk = blockIdx.x, t = threadIdx.x;

    const float* wrow = w + ((long)b * NN + (long)chunk * 64) * EE;
    for (int i = t; i < 64 * EE; i += 192) {
        int e = i & 15;
        disp[i] = __expf(wrow[i] - gmax[b * EE + e]) * grcp[b * EE + e];
    }
    __syncthreads();

    const float* xp;
    int stride;
    if (t < DZ) { xp = z + ((long)b * NN + (long)chunk * 64) * DZ + t; stride = DZ; }
    else        { xp = a + ((long)b * NN + (long)chunk * 64) * DA + (t - DZ); stride = DA; }

    float acc[EE];
#pragma unroll
    for (int e = 0; e < EE; e++) acc[e] = 0.f;

    float A[16], Bv[16];
#pragma unroll
    for (int i = 0; i < 16; i++) A[i] = xp[(long)i * stride];

#pragma unroll
    for (int g = 0; g < 4; g += 2) {
        // prefetch group g+1 into Bv
#pragma unroll
        for (int i = 0; i < 16; i++) Bv[i] = xp[(long)((g + 1) * 16 + i) * stride];
        // compute group g from A
#pragma unroll
        for (int i = 0; i < 16; i++) {
            float xv = A[i];
            const float4* dp = (const float4*)(disp + (g * 16 + i) * EE);
#pragma unroll
            for (int q = 0; q < 4; q++) {
                float4 p = dp[q];
                acc[q * 4 + 0] += p.x * xv;
                acc[q * 4 + 1] += p.y * xv;
                acc[q * 4 + 2] += p.z * xv;
                acc[q * 4 + 3] += p.w * xv;
            }
        }
        // prefetch group g+2 into A
        if (g + 2 < 4) {
#pragma unroll
            for (int i = 0; i < 16; i++) A[i] = xp[(long)((g + 2) * 16 + i) * stride];
        }
        // compute group g+1 from Bv
#pragma unroll
        for (int i = 0; i < 16; i++) {
            float xv = Bv[i];
            const float4* dp = (const float4*)(disp + ((g + 1) * 16 + i) * EE);
#pragma unroll
            for (int q = 0; q < 4; q++) {
                float4 p = dp[q];
                acc[q * 4 + 0] += p.x * xv;
                acc[q * 4 + 1] += p.y * xv;
                acc[q * 4 + 2] += p.z * xv;
                acc[q * 4 + 3] += p.w * xv;
            }
        }
    }

    // xin layout: [e][b][d]
#pragma unroll
    for (int e = 0; e < EE; e++)
        atomicAdd(&xin[((long)e * BB + b) * DD + t], acc[e]);
}

// ---------------- Split-K per-expert GEMM ----------------
template<int K, int OUT, int KSLICE, bool ADD_BIAS>
__global__ __launch_bounds__(256)
void k_gemm(const float* __restrict__ X, const float* __restrict__ W,
            const float* __restrict__ bias, float* __restrict__ Yp) {
    constexpr int SP = KSLICE + 4;
    constexpr int K4 = KSLICE / 4;
    __shared__ float xs[64 * SP];

    int cb = blockIdx.x, ks = blockIdx.y, e = blockIdx.z;
    int t = threadIdx.x;
    int k0 = ks * KSLICE;

    for (int i = t; i < 64 * K4; i += 256) {
        int r = i / K4, k4 = i % K4;
        *(float4*)&xs[r * SP + k4 * 4] =
            *(const float4*)(X + ((long)e * BB + r) * K + k0 + k4 * 4);
    }
    __syncthreads();

    int c = cb * 32 + (t & 7) * 4;
    int r0 = (t >> 3) * 2;
    const float* Wp = W + ((long)e * K + k0) * OUT + c;

    float acc0[4], acc1[4];
#pragma unroll
    for (int j = 0; j < 4; j++) {
        float bv = ADD_BIAS ? bias[(long)e * OUT + c + j] : 0.f;
        acc0[j] = bv;
        acc1[j] = bv;
    }

#pragma unroll 4
    for (int k4 = 0; k4 < K4; k4++) {
        float4 x0 = *(const float4*)&xs[r0 * SP + k4 * 4];
        float4 x1 = *(const float4*)&xs[(r0 + 1) * SP + k4 * 4];
        const float* xp0 = &x0.x;
        const float* xp1 = &x1.x;
#pragma unroll
        for (int j = 0; j < 4; j++) {
            float4 wv = *(const float4*)(Wp + (long)(k4 * 4 + j) * OUT);
            float xa = xp0[j], xb = xp1[j];
            acc0[0] += xa * wv.x; acc0[1] += xa * wv.y;
            acc0[2] += xa * wv.z; acc0[3] += xa * wv.w;
            acc1[0] += xb * wv.x; acc1[1] += xb * wv.y;
            acc1[2] += xb * wv.z; acc1[3] += xb * wv.w;
        }
    }

    float* yp = Yp + ((long)ks * (EE * BB) + (long)e * BB + r0) * OUT + c;
    *(float4*)yp         = make_float4(acc0[0], acc0[1], acc0[2], acc0[3]);
    *(float4*)(yp + OUT) = make_float4(acc1[0], acc1[1], acc1[2], acc1[3]);
}

// Reduce KS partials + bias, then LayerNorm + mish.  One block per row, OUT=512.
template<int KS, bool HAS_BIAS>
__global__ __launch_bounds__(256)
void k_lnact(const float* __restrict__ Yp, const float* __restrict__ bias,
             const float* __restrict__ g, const float* __restrict__ be,
             float* __restrict__ Yo) {
    __shared__ float redS[4], redQ[4];
    int row = blockIdx.x, t = threadIdx.x;
    int e = row >> 6;

    float v[2];
#pragma unroll
    for (int j = 0; j < 2; j++) {
        int cj = t + j * 256;
        float s = HAS_BIAS ? bias[(long)e * HH + cj] : 0.f;
#pragma unroll
        for (int ks = 0; ks < KS; ks++)
            s += Yp[((long)ks * (EE * BB) + row) * HH + cj];
        v[j] = s;
    }
    float s = v[0] + v[1];
    float q = v[0] * v[0] + v[1] * v[1];
    for (int off = 32; off > 0; off >>= 1) {
        s += __shfl_xor(s, off);
        q += __shfl_xor(q, off);
    }
    int wave = t >> 6, lane = t & 63;
    if (lane == 0) { redS[wave] = s; redQ[wave] = q; }
    __syncthreads();
    float S = redS[0] + redS[1] + redS[2] + redS[3];
    float Q = redQ[0] + redQ[1] + redQ[2] + redQ[3];
    float mean = S * (1.f / HH);
    float var = Q * (1.f / HH) - mean * mean;
    float rstd = rsqrtf(var + LN_EPS);

#pragma unroll
    for (int j = 0; j < 2; j++) {
        int cj = t + j * 256;
        float gg = g[(long)e * HH + cj], bb = be[(long)e * HH + cj];
        Yo[(long)row * HH + cj] = mishf((v[j] - mean) * rstd * gg + bb);
    }
}

// Reduce gemm3 partials + bias, scatter to eout[b][e][DZ]. 2 rows per block.
template<int KS>
__global__ __launch_bounds__(256)
void k_fin3(const float* __restrict__ p3, const float* __restrict__ b3,
            float* __restrict__ eout) {
    int t = threadIdx.x;
    int row = blockIdx.x * 2 + (t >> 7);   // 0..1023  (= e*64+b)
    int c = t & 127;
    int e = row >> 6, b = row & 63;
    float s = b3[(long)e * DZ + c];
#pragma unroll
    for (int ks = 0; ks < KS; ks++)
        s += p3[((long)ks * (EE * BB) + row) * DZ + c];
    eout[((long)b * EE + e) * DZ + c] = s;
}

// ---------------- K5: combine softmax over E + mix ----------------
__global__ __launch_bounds__(256)
void k_combine(const float* __restrict__ w, const float* __restrict__ eout,
               float* __restrict__ out) {
    __shared__ float comb[64][EE];
    __shared__ float eo[EE * DZ];   // 8 KB
    int b = blockIdx.y, n0 = blockIdx.x * 64, t = threadIdx.x;

    for (int i = t; i < EE * DZ; i += 256) eo[i] = eout[(long)b * EE * DZ + i];

    int tok = t >> 2, sub = t & 3;
    const float4 wv = *(const float4*)(w + ((long)b * NN + n0 + tok) * EE + sub * 4);
    float mx = fmaxf(fmaxf(wv.x, wv.y), fmaxf(wv.z, wv.w));
    mx = fmaxf(mx, __shfl_xor(mx, 1, 4));
    mx = fmaxf(mx, __shfl_xor(mx, 2, 4));
    float e0 = __expf(wv.x - mx), e1 = __expf(wv.y - mx);
    float e2 = __expf(wv.z - mx), e3 = __expf(wv.w - mx);
    float s = e0 + e1 + e2 + e3;
    s += __shfl_xor(s, 1, 4);
    s += __shfl_xor(s, 2, 4);
    float rs = 1.f / s;
    comb[tok][sub * 4 + 0] = e0 * rs;
    comb[tok][sub * 4 + 1] = e1 * rs;
    comb[tok][sub * 4 + 2] = e2 * rs;
    comb[tok][sub * 4 + 3] = e3 * rs;
    __syncthreads();

    for (int i = t; i < 64 * DZ; i += 256) {
        int tk = i >> 7, c = i & 127;
        float acc = 0.f;
#pragma unroll
        for (int e = 0; e < EE; e++) acc += comb[tk][e] * eo[e * DZ + c];
        out[((long)b * NN + n0 + tk) * DZ + c] = acc;
    }
}

extern "C" void kernel_launch(void* const* d_in, const int* in_sizes, int n_in,
                              void* d_out, int out_size, void* d_ws, size_t ws_size,
                              hipStream_t stream) {
    const float* z   = (const float*)d_in[0];
    const float* a   = (const float*)d_in[1];
    const float* phi = (const float*)d_in[2];
    const float* W1  = (const float*)d_in[3];
    const float* b1  = (const float*)d_in[4];
    const float* g1  = (const float*)d_in[5];
    const float* be1 = (const float*)d_in[6];
    const float* W2  = (const float*)d_in[7];
    const float* b2  = (const float*)d_in[8];
    const float* g2  = (const float*)d_in[9];
    const float* be2 = (const float*)d_in[10];
    const float* W3  = (const float*)d_in[11];
    const float* b3  = (const float*)d_in[12];
    float* out = (float*)d_out;

    char* p = (char*)d_ws;
    float* w    = (float*)p; p += (size_t)BB * NN * EE * 4;          // 8.39 MB
    float* gmax = (float*)p; p += (size_t)BB * EE * 4;
    float* grcp = (float*)p; p += (size_t)BB * EE * 4;
    float* lmax = (float*)p; p += (size_t)BB * 4 * EE * 4;           // 16 KB
    float* lsum = (float*)p; p += (size_t)BB * 4 * EE * 4;           // 16 KB
    float* xin  = (float*)p; p += (size_t)BB * EE * DD * 4;          // 786 KB
    float* part = (float*)p; p += (size_t)4 * EE * BB * HH * 4;      // 8 MB
    float* h1   = (float*)p; p += (size_t)EE * BB * HH * 4;          // 2 MB
    float* h2   = h1;                                                 // time-shared
    float* eout = (float*)p; p += (size_t)BB * EE * DZ * 4;          // 524 KB

    hipMemsetAsync(xin, 0, (size_t)BB * EE * DD * 4, stream);

    k_weights<<<BB * NN / 128, 256, 0, stream>>>(z, a, phi, w);
    k_stats1<<<dim3(4, BB), 256, 0, stream>>>(w, lmax, lsum);
    k_stats2<<<4, 256, 0, stream>>>(lmax, lsum, gmax, grcp);
    k_xin<<<dim3(NN / 64, BB), 192, 0, stream>>>(z, a, w, gmax, grcp, xin);

    // layer 1: 192 -> 512, split-K 2
    k_gemm<DD, HH, 96, false>
        <<<dim3(HH / 32, 2, EE), 256, 0, stream>>>(xin, W1, nullptr, part);
    k_lnact<2, true><<<EE * BB, 256, 0, stream>>>(part, b1, g1, be1, h1);

    // layer 2: 512 -> 512, split-K 4
    k_gemm<HH, HH, 128, false>
        <<<dim3(HH / 32, 4, EE), 256, 0, stream>>>(h1, W2, nullptr, part);
    k_lnact<4, true><<<EE * BB, 256, 0, stream>>>(part, b2, g2, be2, h2);

    // layer 3: 512 -> 128, split-K 8
    k_gemm<HH, DZ, 64, false>
        <<<dim3(DZ / 32, 8, EE), 256, 0, stream>>>(h2, W3, nullptr, part);
    k_fin3<8><<<EE * BB / 2, 256, 0, stream>>>(part, b3, eout);

    k_combine<<<dim3(NN / 64, BB), 256, 0, stream>>>(w, eout, out);
}

// Round 6
// 138.314 us; speedup vs baseline: 1.2531x; 1.2531x over previous
//
#include <hip/hip_runtime.h>
#include <math.h>

#define BB 64
#define NN 2048
#define DZ 128
#define DA 64
#define DD 192
#define EE 16
#define HH 512
#define LN_EPS 1e-5f

typedef __attribute__((ext_vector_type(8))) short short8;
typedef __attribute__((ext_vector_type(4))) float f32x4;

__device__ __forceinline__ float mishf(float x) {
    float sp = (x > 20.f) ? x : log1pf(__expf(x));
    return x * tanhf(sp);
}

__device__ __forceinline__ unsigned short bf16_rne(float f) {
    unsigned u = __float_as_uint(f);
    return (unsigned short)((u + 0x7FFFu + ((u >> 16) & 1u)) >> 16);
}
__device__ __forceinline__ float bf16f(unsigned short h) {
    return __uint_as_float(((unsigned)h) << 16);
}

// ---------------- phi pre-pack: per-lane MFMA B-fragments, bf16 hi/lo ----------------
// layout: [kk<6][lane<64][j<8];  lane: e = lane&15 (col), g = lane>>4; k = kk*32+g*8+j
__global__ __launch_bounds__(256)
void k_phipack(const float* __restrict__ phi, unsigned short* __restrict__ ph,
               unsigned short* __restrict__ pl) {
    int idx = blockIdx.x * 256 + threadIdx.x;      // < 3072
    if (idx >= 6 * 64 * 8) return;
    int j = idx & 7, lane = (idx >> 3) & 63, kk = idx >> 9;
    int e = lane & 15, g = lane >> 4;
    int d = kk * 32 + g * 8 + j;
    float f = phi[d * EE + e];
    unsigned short h = bf16_rne(f);
    ph[idx] = h;
    pl[idx] = bf16_rne(f - bf16f(h));
}

// ---------------- K1: weights = x @ phi via split-bf16 MFMA ----------------
// wave = one 16-token tile; block = 4 waves = 64 tokens; grid 2048.
__global__ __launch_bounds__(256)
void k_weights(const float* __restrict__ z, const float* __restrict__ a,
               const unsigned short* __restrict__ php,
               const unsigned short* __restrict__ plp,
               float* __restrict__ w) {
    int t = threadIdx.x;
    int wv = t >> 6, l = t & 63;
    long tokbase = ((long)blockIdx.x * 4 + wv) * 16;
    long tokA = tokbase + (l & 15);
    int g = l >> 4;

    short8 bh[6], bl[6], ah[6], al[6];
#pragma unroll
    for (int kk = 0; kk < 6; kk++) {
        bh[kk] = *(const short8*)(php + kk * 512 + l * 8);
        bl[kk] = *(const short8*)(plp + kk * 512 + l * 8);
    }
#pragma unroll
    for (int kk = 0; kk < 6; kk++) {
        int d0 = kk * 32 + g * 8;                  // 8-elem chunk never straddles z/a
        const float* src = (d0 < DZ) ? (z + tokA * DZ + d0)
                                     : (a + tokA * DA + (d0 - DZ));
        float4 v0 = ((const float4*)src)[0];
        float4 v1 = ((const float4*)src)[1];
        float f[8] = {v0.x, v0.y, v0.z, v0.w, v1.x, v1.y, v1.z, v1.w};
#pragma unroll
        for (int j = 0; j < 8; j++) {
            unsigned short h = bf16_rne(f[j]);
            ah[kk][j] = (short)h;
            al[kk][j] = (short)bf16_rne(f[j] - bf16f(h));
        }
    }

    f32x4 acc = {0.f, 0.f, 0.f, 0.f};
#pragma unroll
    for (int kk = 0; kk < 6; kk++)
        acc = __builtin_amdgcn_mfma_f32_16x16x32_bf16(ah[kk], bh[kk], acc, 0, 0, 0);
#pragma unroll
    for (int kk = 0; kk < 6; kk++)
        acc = __builtin_amdgcn_mfma_f32_16x16x32_bf16(al[kk], bh[kk], acc, 0, 0, 0);
#pragma unroll
    for (int kk = 0; kk < 6; kk++)
        acc = __builtin_amdgcn_mfma_f32_16x16x32_bf16(ah[kk], bl[kk], acc, 0, 0, 0);

    int e = l & 15;                                 // D: col = lane&15
#pragma unroll
    for (int r = 0; r < 4; r++) {
        long row = tokbase + g * 4 + r;             // D: row = (lane>>4)*4 + r
        w[row * EE + e] = acc[r];
    }
}

// ---------------- K2: softmax stats over n, chunked ----------------
#define RSTR 17
__global__ __launch_bounds__(256)
void k_stats1(const float* __restrict__ w, float* __restrict__ lmax,
              float* __restrict__ lsum) {
    __shared__ float red[256 * RSTR];
    int b = blockIdx.y, c = blockIdx.x, t = threadIdx.x;
    const float* wb = w + ((long)b * NN + c * 512) * EE;

    float m[EE];
#pragma unroll
    for (int e = 0; e < EE; e++) m[e] = -1e30f;
    for (int k = 0; k < 2; k++) {
        const float4* row = (const float4*)(wb + ((long)(k * 256 + t)) * EE);
#pragma unroll
        for (int q = 0; q < 4; q++) {
            float4 v = row[q];
            m[q * 4 + 0] = fmaxf(m[q * 4 + 0], v.x);
            m[q * 4 + 1] = fmaxf(m[q * 4 + 1], v.y);
            m[q * 4 + 2] = fmaxf(m[q * 4 + 2], v.z);
            m[q * 4 + 3] = fmaxf(m[q * 4 + 3], v.w);
        }
    }
#pragma unroll
    for (int e = 0; e < EE; e++) red[t * RSTR + e] = m[e];
    __syncthreads();
    for (int s = 128; s > 0; s >>= 1) {
        if (t < s) {
#pragma unroll
            for (int e = 0; e < EE; e++)
                red[t * RSTR + e] = fmaxf(red[t * RSTR + e], red[(t + s) * RSTR + e]);
        }
        __syncthreads();
    }
    float mg[EE];
#pragma unroll
    for (int e = 0; e < EE; e++) mg[e] = red[e];
    __syncthreads();

    float s_[EE];
#pragma unroll
    for (int e = 0; e < EE; e++) s_[e] = 0.f;
    for (int k = 0; k < 2; k++) {
        const float4* row = (const float4*)(wb + ((long)(k * 256 + t)) * EE);
#pragma unroll
        for (int q = 0; q < 4; q++) {
            float4 v = row[q];
            s_[q * 4 + 0] += __expf(v.x - mg[q * 4 + 0]);
            s_[q * 4 + 1] += __expf(v.y - mg[q * 4 + 1]);
            s_[q * 4 + 2] += __expf(v.z - mg[q * 4 + 2]);
            s_[q * 4 + 3] += __expf(v.w - mg[q * 4 + 3]);
        }
    }
#pragma unroll
    for (int e = 0; e < EE; e++) red[t * RSTR + e] = s_[e];
    __syncthreads();
    for (int s = 128; s > 0; s >>= 1) {
        if (t < s) {
#pragma unroll
            for (int e = 0; e < EE; e++)
                red[t * RSTR + e] += red[(t + s) * RSTR + e];
        }
        __syncthreads();
    }
    if (t < EE) {
        lmax[((long)b * 4 + c) * EE + t] = mg[t];
        lsum[((long)b * 4 + c) * EE + t] = red[t];
    }
}

__global__ __launch_bounds__(256)
void k_stats2(const float* __restrict__ lmax, const float* __restrict__ lsum,
              float* __restrict__ gmax, float* __restrict__ grcp) {
    int idx = blockIdx.x * 256 + threadIdx.x;
    if (idx >= BB * EE) return;
    int b = idx >> 4, e = idx & 15;
    float gm = -1e30f;
#pragma unroll
    for (int c = 0; c < 4; c++)
        gm = fmaxf(gm, lmax[((long)b * 4 + c) * EE + e]);
    float Z = 0.f;
#pragma unroll
    for (int c = 0; c < 4; c++)
        Z += __expf(lmax[((long)b * 4 + c) * EE + e] - gm) * lsum[((long)b * 4 + c) * EE + e];
    gmax[idx] = gm;
    grcp[idx] = 1.f / Z;
}

// ---------------- K3: xin partials (no atomics) ----------------
// 128-token chunks, 16 chunks/b -> 1024 blocks. dst: partial [chunk][e][b][d]
// (or atomic fallback into xin directly when ws is small).
template<bool USE_ATOMIC>
__global__ __launch_bounds__(192)
void k_xin(const float* __restrict__ z, const float* __restrict__ a,
           const float* __restrict__ w, const float* __restrict__ gmax,
           const float* __restrict__ grcp, float* __restrict__ dst) {
    __shared__ float disp[128 * EE];   // 8 KB
    int b = blockIdx.y, chunk = blockIdx.x, t = threadIdx.x;

    const float* wrow = w + ((long)b * NN + (long)chunk * 128) * EE;
    for (int i = t; i < 128 * EE; i += 192) {
        int e = i & 15;
        disp[i] = __expf(wrow[i] - gmax[b * EE + e]) * grcp[b * EE + e];
    }
    __syncthreads();

    const float* xp;
    int stride;
    if (t < DZ) { xp = z + ((long)b * NN + (long)chunk * 128) * DZ + t; stride = DZ; }
    else        { xp = a + ((long)b * NN + (long)chunk * 128) * DA + (t - DZ); stride = DA; }

    float acc[EE];
#pragma unroll
    for (int e = 0; e < EE; e++) acc[e] = 0.f;

    float A[16], Bv[16];
#pragma unroll
    for (int i = 0; i < 16; i++) A[i] = xp[(long)i * stride];

#pragma unroll
    for (int g = 0; g < 8; g += 2) {
#pragma unroll
        for (int i = 0; i < 16; i++) Bv[i] = xp[(long)((g + 1) * 16 + i) * stride];
#pragma unroll
        for (int i = 0; i < 16; i++) {
            float xv = A[i];
            const float4* dp = (const float4*)(disp + (g * 16 + i) * EE);
#pragma unroll
            for (int q = 0; q < 4; q++) {
                float4 p = dp[q];
                acc[q * 4 + 0] += p.x * xv;
                acc[q * 4 + 1] += p.y * xv;
                acc[q * 4 + 2] += p.z * xv;
                acc[q * 4 + 3] += p.w * xv;
            }
        }
        if (g + 2 < 8) {
#pragma unroll
            for (int i = 0; i < 16; i++) A[i] = xp[(long)((g + 2) * 16 + i) * stride];
        }
#pragma unroll
        for (int i = 0; i < 16; i++) {
            float xv = Bv[i];
            const float4* dp = (const float4*)(disp + ((g + 1) * 16 + i) * EE);
#pragma unroll
            for (int q = 0; q < 4; q++) {
                float4 p = dp[q];
                acc[q * 4 + 0] += p.x * xv;
                acc[q * 4 + 1] += p.y * xv;
                acc[q * 4 + 2] += p.z * xv;
                acc[q * 4 + 3] += p.w * xv;
            }
        }
    }

    if constexpr (USE_ATOMIC) {
#pragma unroll
        for (int e = 0; e < EE; e++)
            atomicAdd(&dst[((long)e * BB + b) * DD + t], acc[e]);
    } else {
#pragma unroll
        for (int e = 0; e < EE; e++)
            dst[(((long)chunk * EE + e) * BB + b) * DD + t] = acc[e];
    }
}

// reduce 16 partials -> xin[e][b][d]
__global__ __launch_bounds__(256)
void k_xinred(const float* __restrict__ xinp, float* __restrict__ xin) {
    long i = (long)blockIdx.x * 256 + threadIdx.x;   // < EE*BB*DD = 196608
    float s = 0.f;
#pragma unroll
    for (int c = 0; c < 16; c++)
        s += xinp[(long)c * (EE * BB * DD) + i];
    xin[i] = s;
}

// ---------------- Split-K per-expert GEMM ----------------
template<int K, int OUT, int KSLICE, bool ADD_BIAS>
__global__ __launch_bounds__(256)
void k_gemm(const float* __restrict__ X, const float* __restrict__ W,
            const float* __restrict__ bias, float* __restrict__ Yp) {
    constexpr int SP = KSLICE + 4;
    constexpr int K4 = KSLICE / 4;
    __shared__ float xs[64 * SP];

    int cb = blockIdx.x, ks = blockIdx.y, e = blockIdx.z;
    int t = threadIdx.x;
    int k0 = ks * KSLICE;

    for (int i = t; i < 64 * K4; i += 256) {
        int r = i / K4, k4 = i % K4;
        *(float4*)&xs[r * SP + k4 * 4] =
            *(const float4*)(X + ((long)e * BB + r) * K + k0 + k4 * 4);
    }
    __syncthreads();

    int c = cb * 32 + (t & 7) * 4;
    int r0 = (t >> 3) * 2;
    const float* Wp = W + ((long)e * K + k0) * OUT + c;

    float acc0[4], acc1[4];
#pragma unroll
    for (int j = 0; j < 4; j++) {
        float bv = ADD_BIAS ? bias[(long)e * OUT + c + j] : 0.f;
        acc0[j] = bv;
        acc1[j] = bv;
    }

#pragma unroll 4
    for (int k4 = 0; k4 < K4; k4++) {
        float4 x0 = *(const float4*)&xs[r0 * SP + k4 * 4];
        float4 x1 = *(const float4*)&xs[(r0 + 1) * SP + k4 * 4];
        const float* xp0 = &x0.x;
        const float* xp1 = &x1.x;
#pragma unroll
        for (int j = 0; j < 4; j++) {
            float4 wv = *(const float4*)(Wp + (long)(k4 * 4 + j) * OUT);
            float xa = xp0[j], xb = xp1[j];
            acc0[0] += xa * wv.x; acc0[1] += xa * wv.y;
            acc0[2] += xa * wv.z; acc0[3] += xa * wv.w;
            acc1[0] += xb * wv.x; acc1[1] += xb * wv.y;
            acc1[2] += xb * wv.z; acc1[3] += xb * wv.w;
        }
    }

    float* yp = Yp + ((long)ks * (EE * BB) + (long)e * BB + r0) * OUT + c;
    *(float4*)yp         = make_float4(acc0[0], acc0[1], acc0[2], acc0[3]);
    *(float4*)(yp + OUT) = make_float4(acc1[0], acc1[1], acc1[2], acc1[3]);
}

// Reduce KS partials + bias, then LayerNorm + mish.
template<int KS, bool HAS_BIAS>
__global__ __launch_bounds__(256)
void k_lnact(const float* __restrict__ Yp, const float* __restrict__ bias,
             const float* __restrict__ g, const float* __restrict__ be,
             float* __restrict__ Yo) {
    __shared__ float redS[4], redQ[4];
    int row = blockIdx.x, t = threadIdx.x;
    int e = row >> 6;

    float v[2];
#pragma unroll
    for (int j = 0; j < 2; j++) {
        int cj = t + j * 256;
        float s = HAS_BIAS ? bias[(long)e * HH + cj] : 0.f;
#pragma unroll
        for (int ks = 0; ks < KS; ks++)
            s += Yp[((long)ks * (EE * BB) + row) * HH + cj];
        v[j] = s;
    }
    float s = v[0] + v[1];
    float q = v[0] * v[0] + v[1] * v[1];
    for (int off = 32; off > 0; off >>= 1) {
        s += __shfl_xor(s, off);
        q += __shfl_xor(q, off);
    }
    int wave = t >> 6, lane = t & 63;
    if (lane == 0) { redS[wave] = s; redQ[wave] = q; }
    __syncthreads();
    float S = redS[0] + redS[1] + redS[2] + redS[3];
    float Q = redQ[0] + redQ[1] + redQ[2] + redQ[3];
    float mean = S * (1.f / HH);
    float var = Q * (1.f / HH) - mean * mean;
    float rstd = rsqrtf(var + LN_EPS);

#pragma unroll
    for (int j = 0; j < 2; j++) {
        int cj = t + j * 256;
        float gg = g[(long)e * HH + cj], bb = be[(long)e * HH + cj];
        Yo[(long)row * HH + cj] = mishf((v[j] - mean) * rstd * gg + bb);
    }
}

// Reduce gemm3 partials + bias, scatter to eout[b][e][DZ].
template<int KS>
__global__ __launch_bounds__(256)
void k_fin3(const float* __restrict__ p3, const float* __restrict__ b3,
            float* __restrict__ eout) {
    int t = threadIdx.x;
    int row = blockIdx.x * 2 + (t >> 7);
    int c = t & 127;
    int e = row >> 6, b = row & 63;
    float s = b3[(long)e * DZ + c];
#pragma unroll
    for (int ks = 0; ks < KS; ks++)
        s += p3[((long)ks * (EE * BB) + row) * DZ + c];
    eout[((long)b * EE + e) * DZ + c] = s;
}

// ---------------- K5: combine softmax over E + mix ----------------
__global__ __launch_bounds__(256)
void k_combine(const float* __restrict__ w, const float* __restrict__ eout,
               float* __restrict__ out) {
    __shared__ float comb[64][EE];
    __shared__ float eo[EE * DZ];
    int b = blockIdx.y, n0 = blockIdx.x * 64, t = threadIdx.x;

    for (int i = t; i < EE * DZ; i += 256) eo[i] = eout[(long)b * EE * DZ + i];

    int tok = t >> 2, sub = t & 3;
    const float4 wv = *(const float4*)(w + ((long)b * NN + n0 + tok) * EE + sub * 4);
    float mx = fmaxf(fmaxf(wv.x, wv.y), fmaxf(wv.z, wv.w));
    mx = fmaxf(mx, __shfl_xor(mx, 1, 4));
    mx = fmaxf(mx, __shfl_xor(mx, 2, 4));
    float e0 = __expf(wv.x - mx), e1 = __expf(wv.y - mx);
    float e2 = __expf(wv.z - mx), e3 = __expf(wv.w - mx);
    float s = e0 + e1 + e2 + e3;
    s += __shfl_xor(s, 1, 4);
    s += __shfl_xor(s, 2, 4);
    float rs = 1.f / s;
    comb[tok][sub * 4 + 0] = e0 * rs;
    comb[tok][sub * 4 + 1] = e1 * rs;
    comb[tok][sub * 4 + 2] = e2 * rs;
    comb[tok][sub * 4 + 3] = e3 * rs;
    __syncthreads();

    for (int i = t; i < 64 * DZ; i += 256) {
        int tk = i >> 7, c = i & 127;
        float acc = 0.f;
#pragma unroll
        for (int e = 0; e < EE; e++) acc += comb[tk][e] * eo[e * DZ + c];
        out[((long)b * NN + n0 + tk) * DZ + c] = acc;
    }
}

extern "C" void kernel_launch(void* const* d_in, const int* in_sizes, int n_in,
                              void* d_out, int out_size, void* d_ws, size_t ws_size,
                              hipStream_t stream) {
    const float* z   = (const float*)d_in[0];
    const float* a   = (const float*)d_in[1];
    const float* phi = (const float*)d_in[2];
    const float* W1  = (const float*)d_in[3];
    const float* b1  = (const float*)d_in[4];
    const float* g1  = (const float*)d_in[5];
    const float* be1 = (const float*)d_in[6];
    const float* W2  = (const float*)d_in[7];
    const float* b2  = (const float*)d_in[8];
    const float* g2  = (const float*)d_in[9];
    const float* be2 = (const float*)d_in[10];
    const float* W3  = (const float*)d_in[11];
    const float* b3  = (const float*)d_in[12];
    float* out = (float*)d_out;

    char* p = (char*)d_ws;
    float* w    = (float*)p; p += (size_t)BB * NN * EE * 4;          // 8.39 MB
    float* gmax = (float*)p; p += (size_t)BB * EE * 4;
    float* grcp = (float*)p; p += (size_t)BB * EE * 4;
    float* lmax = (float*)p; p += (size_t)BB * 4 * EE * 4;
    float* lsum = (float*)p; p += (size_t)BB * 4 * EE * 4;
    float* xin  = (float*)p; p += (size_t)BB * EE * DD * 4;          // 786 KB
    unsigned short* php = (unsigned short*)p; p += 6 * 64 * 8 * 2;   // 6 KB
    unsigned short* plp = (unsigned short*)p; p += 6 * 64 * 8 * 2;   // 6 KB
    // REGION: time-shared between xinp (16*786KB = 12.6 MB, phase A) and
    // gemm partials + h1 + eout (11 MB, phase B)
    char* region = p;
    float* xinp = (float*)region;                                    // 12.6 MB
    float* part = (float*)region;                                    // 8.39 MB
    float* h1   = (float*)(region + (size_t)4 * EE * BB * HH * 4);   // 2.1 MB
    float* h2   = h1;
    float* eout = (float*)(region + (size_t)4 * EE * BB * HH * 4
                                  + (size_t)EE * BB * HH * 4);       // 524 KB
    size_t region_off = (size_t)(region - (char*)d_ws);
    size_t need_full = region_off + (size_t)16 * EE * BB * DD * 4;
    bool full = ws_size >= need_full;

    k_phipack<<<12, 256, 0, stream>>>(phi, php, plp);
    k_weights<<<BB * NN / 64, 256, 0, stream>>>(z, a, php, plp, w);
    k_stats1<<<dim3(4, BB), 256, 0, stream>>>(w, lmax, lsum);
    k_stats2<<<4, 256, 0, stream>>>(lmax, lsum, gmax, grcp);

    if (full) {
        k_xin<false><<<dim3(NN / 128, BB), 192, 0, stream>>>(z, a, w, gmax, grcp, xinp);
        k_xinred<<<EE * BB * DD / 256, 256, 0, stream>>>(xinp, xin);
    } else {
        hipMemsetAsync(xin, 0, (size_t)BB * EE * DD * 4, stream);
        k_xin<true><<<dim3(NN / 128, BB), 192, 0, stream>>>(z, a, w, gmax, grcp, xin);
    }

    // layer 1: 192 -> 512, split-K 2
    k_gemm<DD, HH, 96, false>
        <<<dim3(HH / 32, 2, EE), 256, 0, stream>>>(xin, W1, nullptr, part);
    k_lnact<2, true><<<EE * BB, 256, 0, stream>>>(part, b1, g1, be1, h1);

    // layer 2: 512 -> 512, split-K 4
    k_gemm<HH, HH, 128, false>
        <<<dim3(HH / 32, 4, EE), 256, 0, stream>>>(h1, W2, nullptr, part);
    k_lnact<4, true><<<EE * BB, 256, 0, stream>>>(part, b2, g2, be2, h2);

    // layer 3: 512 -> 128, split-K 8
    k_gemm<HH, DZ, 64, false>
        <<<dim3(DZ / 32, 8, EE), 256, 0, stream>>>(h2, W3, nullptr, part);
    k_fin3<8><<<EE * BB / 2, 256, 0, stream>>>(part, b3, eout);

    k_combine<<<dim3(NN / 64, BB), 256, 0, stream>>>(w, eout, out);
}

// Round 7
// 134.403 us; speedup vs baseline: 1.2895x; 1.0291x over previous
//
#include <hip/hip_runtime.h>
#include <math.h>

#define BB 64
#define NN 2048
#define DZ 128
#define DA 64
#define DD 192
#define EE 16
#define HH 512
#define LN_EPS 1e-5f

typedef __attribute__((ext_vector_type(8))) short short8;
typedef __attribute__((ext_vector_type(4))) float f32x4;

__device__ __forceinline__ float mishf(float x) {
    float sp = (x > 20.f) ? x : log1pf(__expf(x));
    return x * tanhf(sp);
}

__device__ __forceinline__ unsigned short bf16_rne(float f) {
    unsigned u = __float_as_uint(f);
    return (unsigned short)((u + 0x7FFFu + ((u >> 16) & 1u)) >> 16);
}
__device__ __forceinline__ float bf16f(unsigned short h) {
    return __uint_as_float(((unsigned)h) << 16);
}

// ---------------- phi pre-pack: per-lane MFMA B-fragments, bf16 hi/lo ----------------
// layout: [kk<6][lane<64][j<8];  lane: e = lane&15 (col), g = lane>>4; k = kk*32+g*8+j
__global__ __launch_bounds__(256)
void k_phipack(const float* __restrict__ phi, unsigned short* __restrict__ ph,
               unsigned short* __restrict__ pl) {
    int idx = blockIdx.x * 256 + threadIdx.x;      // < 3072
    if (idx >= 6 * 64 * 8) return;
    int j = idx & 7, lane = (idx >> 3) & 63, kk = idx >> 9;
    int e = lane & 15, g = lane >> 4;
    int d = kk * 32 + g * 8 + j;
    float f = phi[d * EE + e];
    unsigned short h = bf16_rne(f);
    ph[idx] = h;
    pl[idx] = bf16_rne(f - bf16f(h));
}

// ---------------- K1: weights = x @ phi via split-bf16 MFMA ----------------
// wave = one 16-token tile; block = 4 waves = 64 tokens; grid 2048.
__global__ __launch_bounds__(256)
void k_weights(const float* __restrict__ z, const float* __restrict__ a,
               const unsigned short* __restrict__ php,
               const unsigned short* __restrict__ plp,
               float* __restrict__ w) {
    int t = threadIdx.x;
    int wv = t >> 6, l = t & 63;
    long tokbase = ((long)blockIdx.x * 4 + wv) * 16;
    long tokA = tokbase + (l & 15);
    int g = l >> 4;

    short8 bh[6], bl[6], ah[6], al[6];
#pragma unroll
    for (int kk = 0; kk < 6; kk++) {
        bh[kk] = *(const short8*)(php + kk * 512 + l * 8);
        bl[kk] = *(const short8*)(plp + kk * 512 + l * 8);
    }
#pragma unroll
    for (int kk = 0; kk < 6; kk++) {
        int d0 = kk * 32 + g * 8;                  // 8-elem chunk never straddles z/a
        const float* src = (d0 < DZ) ? (z + tokA * DZ + d0)
                                     : (a + tokA * DA + (d0 - DZ));
        float4 v0 = ((const float4*)src)[0];
        float4 v1 = ((const float4*)src)[1];
        float f[8] = {v0.x, v0.y, v0.z, v0.w, v1.x, v1.y, v1.z, v1.w};
#pragma unroll
        for (int j = 0; j < 8; j++) {
            unsigned short h = bf16_rne(f[j]);
            ah[kk][j] = (short)h;
            al[kk][j] = (short)bf16_rne(f[j] - bf16f(h));
        }
    }

    f32x4 acc = {0.f, 0.f, 0.f, 0.f};
#pragma unroll
    for (int kk = 0; kk < 6; kk++)
        acc = __builtin_amdgcn_mfma_f32_16x16x32_bf16(ah[kk], bh[kk], acc, 0, 0, 0);
#pragma unroll
    for (int kk = 0; kk < 6; kk++)
        acc = __builtin_amdgcn_mfma_f32_16x16x32_bf16(al[kk], bh[kk], acc, 0, 0, 0);
#pragma unroll
    for (int kk = 0; kk < 6; kk++)
        acc = __builtin_amdgcn_mfma_f32_16x16x32_bf16(ah[kk], bl[kk], acc, 0, 0, 0);

    int e = l & 15;                                 // D: col = lane&15
#pragma unroll
    for (int r = 0; r < 4; r++) {
        long row = tokbase + g * 4 + r;             // D: row = (lane>>4)*4 + r
        w[row * EE + e] = acc[r];
    }
}

// ---------------- K2: softmax stats over n, chunked ----------------
#define RSTR 17
__global__ __launch_bounds__(256)
void k_stats1(const float* __restrict__ w, float* __restrict__ lmax,
              float* __restrict__ lsum) {
    __shared__ float red[256 * RSTR];
    int b = blockIdx.y, c = blockIdx.x, t = threadIdx.x;
    const float* wb = w + ((long)b * NN + c * 512) * EE;

    float m[EE];
#pragma unroll
    for (int e = 0; e < EE; e++) m[e] = -1e30f;
    for (int k = 0; k < 2; k++) {
        const float4* row = (const float4*)(wb + ((long)(k * 256 + t)) * EE);
#pragma unroll
        for (int q = 0; q < 4; q++) {
            float4 v = row[q];
            m[q * 4 + 0] = fmaxf(m[q * 4 + 0], v.x);
            m[q * 4 + 1] = fmaxf(m[q * 4 + 1], v.y);
            m[q * 4 + 2] = fmaxf(m[q * 4 + 2], v.z);
            m[q * 4 + 3] = fmaxf(m[q * 4 + 3], v.w);
        }
    }
#pragma unroll
    for (int e = 0; e < EE; e++) red[t * RSTR + e] = m[e];
    __syncthreads();
    for (int s = 128; s > 0; s >>= 1) {
        if (t < s) {
#pragma unroll
            for (int e = 0; e < EE; e++)
                red[t * RSTR + e] = fmaxf(red[t * RSTR + e], red[(t + s) * RSTR + e]);
        }
        __syncthreads();
    }
    float mg[EE];
#pragma unroll
    for (int e = 0; e < EE; e++) mg[e] = red[e];
    __syncthreads();

    float s_[EE];
#pragma unroll
    for (int e = 0; e < EE; e++) s_[e] = 0.f;
    for (int k = 0; k < 2; k++) {
        const float4* row = (const float4*)(wb + ((long)(k * 256 + t)) * EE);
#pragma unroll
        for (int q = 0; q < 4; q++) {
            float4 v = row[q];
            s_[q * 4 + 0] += __expf(v.x - mg[q * 4 + 0]);
            s_[q * 4 + 1] += __expf(v.y - mg[q * 4 + 1]);
            s_[q * 4 + 2] += __expf(v.z - mg[q * 4 + 2]);
            s_[q * 4 + 3] += __expf(v.w - mg[q * 4 + 3]);
        }
    }
#pragma unroll
    for (int e = 0; e < EE; e++) red[t * RSTR + e] = s_[e];
    __syncthreads();
    for (int s = 128; s > 0; s >>= 1) {
        if (t < s) {
#pragma unroll
            for (int e = 0; e < EE; e++)
                red[t * RSTR + e] += red[(t + s) * RSTR + e];
        }
        __syncthreads();
    }
    if (t < EE) {
        lmax[((long)b * 4 + c) * EE + t] = mg[t];
        lsum[((long)b * 4 + c) * EE + t] = red[t];
    }
}

__global__ __launch_bounds__(256)
void k_stats2(const float* __restrict__ lmax, const float* __restrict__ lsum,
              float* __restrict__ gmax, float* __restrict__ grcp) {
    int idx = blockIdx.x * 256 + threadIdx.x;
    if (idx >= BB * EE) return;
    int b = idx >> 4, e = idx & 15;
    float gm = -1e30f;
#pragma unroll
    for (int c = 0; c < 4; c++)
        gm = fmaxf(gm, lmax[((long)b * 4 + c) * EE + e]);
    float Z = 0.f;
#pragma unroll
    for (int c = 0; c < 4; c++)
        Z += __expf(lmax[((long)b * 4 + c) * EE + e] - gm) * lsum[((long)b * 4 + c) * EE + e];
    gmax[idx] = gm;
    grcp[idx] = 1.f / Z;
}

// ---------------- K3 (new): xin = disp^T @ x via split-bf16 MFMA ----------------
// block = (K-quarter kq of 128 tokens, b); 4 waves; wave wv owns d-tiles wv*3..wv*3+2.
// Block collectively reads FULL x rows -> perfect line utilization, x read once.
// A-frag (disp, row=e=lane&15) computed on the fly from w; B-frag (x, col=d) hi/lo.
__global__ __launch_bounds__(256)
void k_xin2(const float* __restrict__ z, const float* __restrict__ a,
            const float* __restrict__ w, const float* __restrict__ gmax,
            const float* __restrict__ grcp, float* __restrict__ pxin) {
    int kq = blockIdx.x, b = blockIdx.y;
    int t = threadIdx.x, wv = t >> 6, l = t & 63;
    int g = l >> 4, c = l & 15;

    float gm = gmax[b * EE + c];
    float gr = grcp[b * EE + c];
    const float* wb = w + ((long)b * NN + (long)kq * 128) * EE;
    const float* zb = z + ((long)b * NN + (long)kq * 128) * DZ;
    const float* ab = a + ((long)b * NN + (long)kq * 128) * DA;

    f32x4 acc0 = {0.f, 0.f, 0.f, 0.f};
    f32x4 acc1 = {0.f, 0.f, 0.f, 0.f};
    f32x4 acc2 = {0.f, 0.f, 0.f, 0.f};

#pragma unroll
    for (int kk = 0; kk < 4; kk++) {
        int nb = kk * 32 + g * 8;          // n offset within 128-slice; k-slot base
        // A: dispatch fragment, row = e = c
        short8 ad;
#pragma unroll
        for (int j = 0; j < 8; j++) {
            float wvv = wb[(long)(nb + j) * EE + c];
            ad[j] = (short)bf16_rne(__expf(wvv - gm) * gr);
        }
        // B: three d-tiles, col = d = (wv*3+i)*16 + c, split hi/lo
#pragma unroll
        for (int i = 0; i < 3; i++) {
            int d = (wv * 3 + i) * 16 + c;
            short8 xh_, xl_;
#pragma unroll
            for (int j = 0; j < 8; j++) {
                float f = (d < DZ) ? zb[(long)(nb + j) * DZ + d]
                                   : ab[(long)(nb + j) * DA + (d - DZ)];
                unsigned short h = bf16_rne(f);
                xh_[j] = (short)h;
                xl_[j] = (short)bf16_rne(f - bf16f(h));
            }
            if (i == 0) {
                acc0 = __builtin_amdgcn_mfma_f32_16x16x32_bf16(ad, xh_, acc0, 0, 0, 0);
                acc0 = __builtin_amdgcn_mfma_f32_16x16x32_bf16(ad, xl_, acc0, 0, 0, 0);
            } else if (i == 1) {
                acc1 = __builtin_amdgcn_mfma_f32_16x16x32_bf16(ad, xh_, acc1, 0, 0, 0);
                acc1 = __builtin_amdgcn_mfma_f32_16x16x32_bf16(ad, xl_, acc1, 0, 0, 0);
            } else {
                acc2 = __builtin_amdgcn_mfma_f32_16x16x32_bf16(ad, xh_, acc2, 0, 0, 0);
                acc2 = __builtin_amdgcn_mfma_f32_16x16x32_bf16(ad, xl_, acc2, 0, 0, 0);
            }
        }
    }

    // D: col = d-in-tile = c, row = e = g*4 + r.  pxin[kq][e*BB+b][DD]
    float* pb = pxin + (long)kq * (EE * BB * DD) + (long)b * DD;
#pragma unroll
    for (int r = 0; r < 4; r++) {
        int e = g * 4 + r;
        float* pr = pb + (long)e * (BB * DD);
        pr[(wv * 3 + 0) * 16 + c] = acc0[r];
        pr[(wv * 3 + 1) * 16 + c] = acc1[r];
        pr[(wv * 3 + 2) * 16 + c] = acc2[r];
    }
}

// ---------------- K3 fallback (atomic, small-ws): scalar formulation ----------------
__global__ __launch_bounds__(192)
void k_xin_scalar(const float* __restrict__ z, const float* __restrict__ a,
                  const float* __restrict__ w, const float* __restrict__ gmax,
                  const float* __restrict__ grcp, float* __restrict__ dst) {
    __shared__ float disp[128 * EE];   // 8 KB
    int b = blockIdx.y, chunk = blockIdx.x, t = threadIdx.x;

    const float* wrow = w + ((long)b * NN + (long)chunk * 128) * EE;
    for (int i = t; i < 128 * EE; i += 192) {
        int e = i & 15;
        disp[i] = __expf(wrow[i] - gmax[b * EE + e]) * grcp[b * EE + e];
    }
    __syncthreads();

    const float* xp;
    int stride;
    if (t < DZ) { xp = z + ((long)b * NN + (long)chunk * 128) * DZ + t; stride = DZ; }
    else        { xp = a + ((long)b * NN + (long)chunk * 128) * DA + (t - DZ); stride = DA; }

    float acc[EE];
#pragma unroll
    for (int e = 0; e < EE; e++) acc[e] = 0.f;

    for (int n = 0; n < 128; n++) {
        float xv = xp[(long)n * stride];
        const float4* dp = (const float4*)(disp + n * EE);
#pragma unroll
        for (int q = 0; q < 4; q++) {
            float4 p = dp[q];
            acc[q * 4 + 0] += p.x * xv;
            acc[q * 4 + 1] += p.y * xv;
            acc[q * 4 + 2] += p.z * xv;
            acc[q * 4 + 3] += p.w * xv;
        }
    }
#pragma unroll
    for (int e = 0; e < EE; e++)
        atomicAdd(&dst[((long)e * BB + b) * DD + t], acc[e]);
}

// reduce 16 partials -> xin[e][b][d]
__global__ __launch_bounds__(256)
void k_xinred(const float* __restrict__ xinp, float* __restrict__ xin) {
    long i = (long)blockIdx.x * 256 + threadIdx.x;   // < EE*BB*DD = 196608
    float s = 0.f;
#pragma unroll
    for (int c = 0; c < 16; c++)
        s += xinp[(long)c * (EE * BB * DD) + i];
    xin[i] = s;
}

// ---------------- Split-K per-expert GEMM ----------------
template<int K, int OUT, int KSLICE, bool ADD_BIAS>
__global__ __launch_bounds__(256)
void k_gemm(const float* __restrict__ X, const float* __restrict__ W,
            const float* __restrict__ bias, float* __restrict__ Yp) {
    constexpr int SP = KSLICE + 4;
    constexpr int K4 = KSLICE / 4;
    __shared__ float xs[64 * SP];

    int cb = blockIdx.x, ks = blockIdx.y, e = blockIdx.z;
    int t = threadIdx.x;
    int k0 = ks * KSLICE;

    for (int i = t; i < 64 * K4; i += 256) {
        int r = i / K4, k4 = i % K4;
        *(float4*)&xs[r * SP + k4 * 4] =
            *(const float4*)(X + ((long)e * BB + r) * K + k0 + k4 * 4);
    }
    __syncthreads();

    int c = cb * 32 + (t & 7) * 4;
    int r0 = (t >> 3) * 2;
    const float* Wp = W + ((long)e * K + k0) * OUT + c;

    float acc0[4], acc1[4];
#pragma unroll
    for (int j = 0; j < 4; j++) {
        float bv = ADD_BIAS ? bias[(long)e * OUT + c + j] : 0.f;
        acc0[j] = bv;
        acc1[j] = bv;
    }

#pragma unroll 4
    for (int k4 = 0; k4 < K4; k4++) {
        float4 x0 = *(const float4*)&xs[r0 * SP + k4 * 4];
        float4 x1 = *(const float4*)&xs[(r0 + 1) * SP + k4 * 4];
        const float* xp0 = &x0.x;
        const float* xp1 = &x1.x;
#pragma unroll
        for (int j = 0; j < 4; j++) {
            float4 wv = *(const float4*)(Wp + (long)(k4 * 4 + j) * OUT);
            float xa = xp0[j], xb = xp1[j];
            acc0[0] += xa * wv.x; acc0[1] += xa * wv.y;
            acc0[2] += xa * wv.z; acc0[3] += xa * wv.w;
            acc1[0] += xb * wv.x; acc1[1] += xb * wv.y;
            acc1[2] += xb * wv.z; acc1[3] += xb * wv.w;
        }
    }

    float* yp = Yp + ((long)ks * (EE * BB) + (long)e * BB + r0) * OUT + c;
    *(float4*)yp         = make_float4(acc0[0], acc0[1], acc0[2], acc0[3]);
    *(float4*)(yp + OUT) = make_float4(acc1[0], acc1[1], acc1[2], acc1[3]);
}

// Reduce KS partials + bias, then LayerNorm + mish.
template<int KS, bool HAS_BIAS>
__global__ __launch_bounds__(256)
void k_lnact(const float* __restrict__ Yp, const float* __restrict__ bias,
             const float* __restrict__ g, const float* __restrict__ be,
             float* __restrict__ Yo) {
    __shared__ float redS[4], redQ[4];
    int row = blockIdx.x, t = threadIdx.x;
    int e = row >> 6;

    float v[2];
#pragma unroll
    for (int j = 0; j < 2; j++) {
        int cj = t + j * 256;
        float s = HAS_BIAS ? bias[(long)e * HH + cj] : 0.f;
#pragma unroll
        for (int ks = 0; ks < KS; ks++)
            s += Yp[((long)ks * (EE * BB) + row) * HH + cj];
        v[j] = s;
    }
    float s = v[0] + v[1];
    float q = v[0] * v[0] + v[1] * v[1];
    for (int off = 32; off > 0; off >>= 1) {
        s += __shfl_xor(s, off);
        q += __shfl_xor(q, off);
    }
    int wave = t >> 6, lane = t & 63;
    if (lane == 0) { redS[wave] = s; redQ[wave] = q; }
    __syncthreads();
    float S = redS[0] + redS[1] + redS[2] + redS[3];
    float Q = redQ[0] + redQ[1] + redQ[2] + redQ[3];
    float mean = S * (1.f / HH);
    float var = Q * (1.f / HH) - mean * mean;
    float rstd = rsqrtf(var + LN_EPS);

#pragma unroll
    for (int j = 0; j < 2; j++) {
        int cj = t + j * 256;
        float gg = g[(long)e * HH + cj], bb = be[(long)e * HH + cj];
        Yo[(long)row * HH + cj] = mishf((v[j] - mean) * rstd * gg + bb);
    }
}

// Reduce gemm3 partials + bias, scatter to eout[b][e][DZ].
template<int KS>
__global__ __launch_bounds__(256)
void k_fin3(const float* __restrict__ p3, const float* __restrict__ b3,
            float* __restrict__ eout) {
    int t = threadIdx.x;
    int row = blockIdx.x * 2 + (t >> 7);
    int c = t & 127;
    int e = row >> 6, b = row & 63;
    float s = b3[(long)e * DZ + c];
#pragma unroll
    for (int ks = 0; ks < KS; ks++)
        s += p3[((long)ks * (EE * BB) + row) * DZ + c];
    eout[((long)b * EE + e) * DZ + c] = s;
}

// ---------------- K5: combine softmax over E + mix ----------------
__global__ __launch_bounds__(256)
void k_combine(const float* __restrict__ w, const float* __restrict__ eout,
               float* __restrict__ out) {
    __shared__ float comb[64][EE];
    __shared__ float eo[EE * DZ];
    int b = blockIdx.y, n0 = blockIdx.x * 64, t = threadIdx.x;

    for (int i = t; i < EE * DZ; i += 256) eo[i] = eout[(long)b * EE * DZ + i];

    int tok = t >> 2, sub = t & 3;
    const float4 wv = *(const float4*)(w + ((long)b * NN + n0 + tok) * EE + sub * 4);
    float mx = fmaxf(fmaxf(wv.x, wv.y), fmaxf(wv.z, wv.w));
    mx = fmaxf(mx, __shfl_xor(mx, 1, 4));
    mx = fmaxf(mx, __shfl_xor(mx, 2, 4));
    float e0 = __expf(wv.x - mx), e1 = __expf(wv.y - mx);
    float e2 = __expf(wv.z - mx), e3 = __expf(wv.w - mx);
    float s = e0 + e1 + e2 + e3;
    s += __shfl_xor(s, 1, 4);
    s += __shfl_xor(s, 2, 4);
    float rs = 1.f / s;
    comb[tok][sub * 4 + 0] = e0 * rs;
    comb[tok][sub * 4 + 1] = e1 * rs;
    comb[tok][sub * 4 + 2] = e2 * rs;
    comb[tok][sub * 4 + 3] = e3 * rs;
    __syncthreads();

    for (int i = t; i < 64 * DZ; i += 256) {
        int tk = i >> 7, c = i & 127;
        float acc = 0.f;
#pragma unroll
        for (int e = 0; e < EE; e++) acc += comb[tk][e] * eo[e * DZ + c];
        out[((long)b * NN + n0 + tk) * DZ + c] = acc;
    }
}

extern "C" void kernel_launch(void* const* d_in, const int* in_sizes, int n_in,
                              void* d_out, int out_size, void* d_ws, size_t ws_size,
                              hipStream_t stream) {
    const float* z   = (const float*)d_in[0];
    const float* a   = (const float*)d_in[1];
    const float* phi = (const float*)d_in[2];
    const float* W1  = (const float*)d_in[3];
    const float* b1  = (const float*)d_in[4];
    const float* g1  = (const float*)d_in[5];
    const float* be1 = (const float*)d_in[6];
    const float* W2  = (const float*)d_in[7];
    const float* b2  = (const float*)d_in[8];
    const float* g2  = (const float*)d_in[9];
    const float* be2 = (const float*)d_in[10];
    const float* W3  = (const float*)d_in[11];
    const float* b3  = (const float*)d_in[12];
    float* out = (float*)d_out;

    char* p = (char*)d_ws;
    float* w    = (float*)p; p += (size_t)BB * NN * EE * 4;          // 8.39 MB
    float* gmax = (float*)p; p += (size_t)BB * EE * 4;
    float* grcp = (float*)p; p += (size_t)BB * EE * 4;
    float* lmax = (float*)p; p += (size_t)BB * 4 * EE * 4;
    float* lsum = (float*)p; p += (size_t)BB * 4 * EE * 4;
    float* xin  = (float*)p; p += (size_t)BB * EE * DD * 4;          // 786 KB
    unsigned short* php = (unsigned short*)p; p += 6 * 64 * 8 * 2;   // 6 KB
    unsigned short* plp = (unsigned short*)p; p += 6 * 64 * 8 * 2;   // 6 KB
    // REGION: time-shared between pxin (16*786KB = 12.6 MB, phase A) and
    // gemm partials + h1 + eout (11 MB, phase B)
    char* region = p;
    float* pxin = (float*)region;                                    // 12.6 MB
    float* part = (float*)region;                                    // 8.39 MB
    float* h1   = (float*)(region + (size_t)4 * EE * BB * HH * 4);   // 2.1 MB
    float* h2   = h1;
    float* eout = (float*)(region + (size_t)4 * EE * BB * HH * 4
                                  + (size_t)EE * BB * HH * 4);       // 524 KB
    size_t region_off = (size_t)(region - (char*)d_ws);
    size_t need_full = region_off + (size_t)16 * EE * BB * DD * 4;
    bool full = ws_size >= need_full;

    k_phipack<<<12, 256, 0, stream>>>(phi, php, plp);
    k_weights<<<BB * NN / 64, 256, 0, stream>>>(z, a, php, plp, w);
    k_stats1<<<dim3(4, BB), 256, 0, stream>>>(w, lmax, lsum);
    k_stats2<<<4, 256, 0, stream>>>(lmax, lsum, gmax, grcp);

    if (full) {
        k_xin2<<<dim3(16, BB), 256, 0, stream>>>(z, a, w, gmax, grcp, pxin);
        k_xinred<<<EE * BB * DD / 256, 256, 0, stream>>>(pxin, xin);
    } else {
        hipMemsetAsync(xin, 0, (size_t)BB * EE * DD * 4, stream);
        k_xin_scalar<<<dim3(NN / 128, BB), 192, 0, stream>>>(z, a, w, gmax, grcp, xin);
    }

    // layer 1: 192 -> 512, split-K 2
    k_gemm<DD, HH, 96, false>
        <<<dim3(HH / 32, 2, EE), 256, 0, stream>>>(xin, W1, nullptr, part);
    k_lnact<2, true><<<EE * BB, 256, 0, stream>>>(part, b1, g1, be1, h1);

    // layer 2: 512 -> 512, split-K 4
    k_gemm<HH, HH, 128, false>
        <<<dim3(HH / 32, 4, EE), 256, 0, stream>>>(h1, W2, nullptr, part);
    k_lnact<4, true><<<EE * BB, 256, 0, stream>>>(part, b2, g2, be2, h2);

    // layer 3: 512 -> 128, split-K 8
    k_gemm<HH, DZ, 64, false>
        <<<dim3(DZ / 32, 8, EE), 256, 0, stream>>>(h2, W3, nullptr, part);
    k_fin3<8><<<EE * BB / 2, 256, 0, stream>>>(part, b3, eout);

    k_combine<<<dim3(NN / 64, BB), 256, 0, stream>>>(w, eout, out);
}